// Round 11
// baseline (23.620 us; speedup 1.0000x reference)
//
#include <hip/hip_runtime.h>
#include <math.h>

namespace {

constexpr int NX  = 512;    // data points
constexpr int M   = 514;    // basis functions
constexpr int NE  = 8192;   // eval points
constexpr int NBC = 256;    // batch*channels
constexpr int WARM = 10;    // warm-up rows (rel err ~0.268^10 ~ 2e-6, threshold 9e-2)

constexpr int PPB  = 16;    // eval points per block
constexpr int BCG  = 128;   // bc rows per block (2 halves)
constexpr int NBLK = (NE / PPB) * (NBC / BCG);   // 1024 blocks -> 4 blocks/CU
constexpr int CHUNKS = 8;   // float4 chunks staged per bc row
constexpr int SLOTS  = CHUNKS * 4;  // 32 staged columns (need <= 28+d)
constexpr int STRIDE = 33;  // odd -> <=2-way LDS bank conflicts (free)

// ---------------------------------------------------------------------------
// Compile-time tables: basis weights and banded Cholesky factor (double math).
// ---------------------------------------------------------------------------
constexpr double dknot(int j) {
    int c = j - 3;
    c = c < 0 ? 0 : (c > NX - 1 ? NX - 1 : c);
    return -1.0 + 2.0 * (double)c / 511.0;
}

constexpr double csqrt(double x) {
    double r = x > 1.0 ? x : 1.0;
    for (int k = 0; k < 50; ++k) r = 0.5 * (r + x / r);
    return r;
}

struct Tables {
    alignas(16) float lb[M + 3][4];  // rd=1/diag, l1, l2, l3 (3 zero pad rows)
    alignas(16) float w4[M][4];      // w4[i][r] = weight of Z[i-r] in Btz[i] (0 if OOR)
    float we[4];                     // weight of Z[511] in Btz[510+q]
};

constexpr Tables make_tables() {
    Tables T{};
    double bx[NX][4] = {};
    for (int n = 0; n < NX; ++n) {
        const int off = n < NX - 1 ? n : NX - 2;
        const double x = -1.0 + 2.0 * (double)n / 511.0;
        double N[4] = {1.0, 0.0, 0.0, 0.0};
        for (int d = 1; d <= 3; ++d) {
            double saved = 0.0;
            for (int r = 0; r < d; ++r) {
                const double tr = dknot(off + 3 + r + 1);
                const double tl = dknot(off + 3 + r + 1 - d);
                const double temp = N[r] / (tr - tl);
                N[r] = saved + (tr - x) * temp;
                saved = (x - tl) * temp;
            }
            N[d] = saved;
        }
        for (int r = 0; r < 4; ++r) bx[n][r] = N[r];
    }
    double A[M][4] = {};
    for (int i = 0; i < M; ++i) {
        double a0 = 1e-3, a1 = 0.0, a2 = 0.0, a3 = 0.0;
        const int nlo = i - 3 < 0 ? 0 : i - 3;
        const int nhi = i + 1 > NX - 1 ? NX - 1 : i + 1;
        for (int n = nlo; n <= nhi; ++n) {
            const int off = n < NX - 1 ? n : NX - 2;
            const int ri = i - off;
            if (ri < 0 || ri > 3) continue;
            const double bi = bx[n][ri];
            a0 += bi * bx[n][ri];
            if (ri >= 1) a1 += bi * bx[n][ri - 1];
            if (ri >= 2) a2 += bi * bx[n][ri - 2];
            if (ri >= 3) a3 += bi * bx[n][ri - 3];
        }
        A[i][0] = a0; A[i][1] = a1; A[i][2] = a2; A[i][3] = a3;
    }
    {
        double rd1 = 0.0, l1p = 0.0, l2p = 0.0, rd2 = 0.0, l1pp = 0.0, rd3 = 0.0;
        for (int i = 0; i < M; ++i) {
            const double l3 = A[i][3] * rd3;
            const double l2 = (A[i][2] - l3 * l1pp) * rd2;
            const double l1 = (A[i][1] - l3 * l2p - l2 * l1p) * rd1;
            const double s  = A[i][0] - l3 * l3 - l2 * l2 - l1 * l1;
            const double rd = 1.0 / csqrt(s);
            T.lb[i][0] = (float)rd; T.lb[i][1] = (float)l1;
            T.lb[i][2] = (float)l2; T.lb[i][3] = (float)l3;
            rd3 = rd2; rd2 = rd1; rd1 = rd;
            l1pp = l1p; l1p = l1; l2p = l2;
        }
    }
    for (int i = 0; i < M; ++i)
        for (int r = 0; r < 4; ++r) {
            const int n = i - r;
            T.w4[i][r] = (n >= 0 && n <= NX - 2) ? (float)bx[n][r] : 0.0f;
        }
    for (int q = 0; q < 4; ++q) T.we[q] = (float)bx[NX - 1][q];
    return T;
}

__constant__ Tables TBL = make_tables();

// interior (Toeplitz / converged) constants as compile-time immediates
constexpr Tables HT = make_tables();
constexpr float CW0 = HT.w4[256][0], CW1 = HT.w4[256][1], CW2 = HT.w4[256][2], CW3 = HT.w4[256][3];
constexpr float CRD = HT.lb[256][0], CL1 = HT.lb[256][1], CL2 = HT.lb[256][2], CL3 = HT.lb[256][3];
constexpr int INT_LO = 48, INT_HI = 462;

// interval index of eval point n (single fp32 path everywhere)
__device__ __forceinline__ int offf(int n) {
    const float xe = -1.0f + 2.0f * (float)n / 8191.0f;
    int off = (int)((xe + 1.0f) * 255.5f);
    return off < 0 ? 0 : (off > NX - 2 ? NX - 2 : off);
}

__device__ __forceinline__ float knotf(int j) {
    int c = j - 3;
    c = c < 0 ? 0 : (c > NX - 1 ? NX - 1 : c);
    return -1.0f + 2.0f * (float)c / 511.0f;
}

__device__ __forceinline__ void deboor3(float x, int j, float N[4]) {
    N[0] = 1.0f; N[1] = 0.0f; N[2] = 0.0f; N[3] = 0.0f;
#pragma unroll
    for (int d = 1; d <= 3; ++d) {
        float saved = 0.0f;
#pragma unroll
        for (int r = 0; r < 3; ++r) {
            if (r < d) {
                const float tr = knotf(j + r + 1);
                const float tl = knotf(j + r + 1 - d);
                const float temp = N[r] / (tr - tl);
                N[r] = saved + (tr - x) * temp;
                saved = (x - tl) * temp;
            }
        }
        N[d] = saved;
    }
}

// ---------------------------------------------------------------------------
// Single fused kernel. Block = (point-group pg: 16 points) x (bc-half: 128
// rows). Stage the Z window with 4 float4 loads/thread into LDS (row per bc,
// odd stride 33, slot shift d for alignment), run warm-up fwd+bwd banded
// substitution on lanes 0..127 (slot i-i0: Z col i-3 -> y_i -> coef_i in
// place), then all 256 threads evaluate 8 points each (2 float4 stores).
// 16.9 KB LDS, grid 1024 -> 4 blocks/CU.
// ---------------------------------------------------------------------------
__global__ __launch_bounds__(256) void spline_fused(const float* __restrict__ Z,
                                                    float* __restrict__ out) {
    __shared__ float Bs[BCG * STRIDE + 12];   // +12 pad for fwd over-read
    const int tid = threadIdx.x;
    const int pg  = blockIdx.x >> 1;          // point group 0..511
    const int bc0 = (blockIdx.x & 1) << 7;    // bc half base: 0 or 128
    const int ns  = pg * PPB;

    // wave-uniform geometry
    const int e_lo = offf(ns);                    // first coef row eval needs
    const int e_hi = offf(ns + PPB - 1) + 3;      // last coef row eval needs
    int i0 = e_lo - WARM;  i0 = i0 < 0 ? 0 : i0;  // forward start (exact if 0)
    int i_end = e_hi + WARM;  i_end = i_end > M - 1 ? M - 1 : i_end;
    const int n0 = i0 - 3;                        // first needed Z column
    const int n0a = n0 & ~3;                      // aligned staging base
    const int d = n0 - n0a;                       // slot shift 0..3 (wave-uniform)
    const int NRr = i_end - i0 + 1;               // forward rows  (<= 25)
    const int NRb = i_end - e_lo + 1;             // backward rows (<= 15)

    // ---- stage: 4 float4 loads/thread, fully coalesced ----
    {
        const int ch = tid & 7;        // chunk 0..7
        const int rg = tid >> 3;       // row group 0..31
        int cb = n0a + (ch << 2);
        cb = cb < 0 ? 0 : (cb > NX - 4 ? NX - 4 : cb);  // OOR slots have zero weight
        float4 v[4];
#pragma unroll
        for (int p = 0; p < 4; ++p) {
            const int row = rg + (p << 5);
            v[p] = *(const float4*)(Z + (size_t)(bc0 + row) * NX + cb);
        }
#pragma unroll
        for (int p = 0; p < 4; ++p) {
            const int row = rg + (p << 5);
            float* wp = Bs + row * STRIDE + (ch << 2);   // scalar writes: odd stride
            wp[0] = v[p].x; wp[1] = v[p].y; wp[2] = v[p].z; wp[3] = v[p].w;
        }
    }
    __syncthreads();

    // ---- fwd + bwd substitution on lanes 0..127 (lane = bc row) ----
    if (tid < BCG) {
        float* Brow = Bs + tid * STRIDE + d;   // Brow[s] = col n0+s, then y/coef
        const int s511 = 511 - n0;             // slot of Z col 511
        const float z511 = (s511 >= 0 && s511 < SLOTS - d) ? Brow[s511] : 0.0f;

        float y1 = 0.f, y2 = 0.f, y3 = 0.f;
        const int nfb = (NRr + 7) >> 3;
        for (int cc = 0; cc < nfb; ++cc) {
            const int ri = cc << 3;
            const int ib = i0 + ri;
            float zb[11];
#pragma unroll
            for (int m = 0; m < 11; ++m) zb[m] = Brow[ri + m];   // over-read padded/garbage-safe
            if (ib >= INT_LO && ib + 7 <= INT_HI) {
#pragma unroll
                for (int k = 0; k < 8; ++k) {
                    const float btz = CW0 * zb[k + 3] + CW1 * zb[k + 2] + CW2 * zb[k + 1] + CW3 * zb[k];
                    const float y = (btz - CL1 * y1 - CL2 * y2 - CL3 * y3) * CRD;
                    if (ri + k < NRr) Brow[ri + k] = y;
                    y3 = y2; y2 = y1; y1 = y;
                }
            } else {
#pragma unroll
                for (int k = 0; k < 8; ++k) {
                    const int i = ib + k;
                    const int it = i < M ? i : M - 1;
                    const float4 w = *(const float4*)TBL.w4[it];
                    const float4 l = *(const float4*)TBL.lb[it];
                    float btz = w.x * zb[k + 3] + w.y * zb[k + 2] + w.z * zb[k + 1] + w.w * zb[k];
                    const int q = it - 510;
                    if (q >= 0) btz += TBL.we[q] * z511;
                    const float y = (btz - l.y * y1 - l.z * y2 - l.w * y3) * l.x;
                    if (ri + k < NRr) Brow[ri + k] = y;
                    y3 = y2; y2 = y1; y1 = y;
                }
            }
        }

        // backward: coef overwrites y in place
        const int top = i_end - i0;
        float c1 = 0.f, c2 = 0.f, c3 = 0.f;
        const int nbb = (NRb + 7) >> 3;
        for (int cc = 0; cc < nbb; ++cc) {
            const int ib = i_end - (cc << 3);
            float zb[8];
#pragma unroll
            for (int k = 0; k < 8; ++k) {
                int s = top - (cc << 3) - k;
                zb[k] = Brow[s < 0 ? 0 : s];
            }
            if (ib - 7 >= INT_LO && ib <= INT_HI) {
#pragma unroll
                for (int k = 0; k < 8; ++k) {
                    const int i = ib - k;
                    const float c = (zb[k] - CL1 * c1 - CL2 * c2 - CL3 * c3) * CRD;
                    if ((cc << 3) + k < NRb) Brow[i - i0] = c;
                    c3 = c2; c2 = c1; c1 = c;
                }
            } else {
#pragma unroll
                for (int k = 0; k < 8; ++k) {
                    const int i = ib - k;
                    const int it = i < 0 ? 0 : i;
                    const float rd = TBL.lb[it][0];
                    const float e1 = TBL.lb[it + 1][1];
                    const float e2 = TBL.lb[it + 2][2];
                    const float e3 = TBL.lb[it + 3][3];
                    const float c = (zb[k] - e1 * c1 - e2 * c2 - e3 * c3) * rd;
                    if ((cc << 3) + k < NRb) Brow[i - i0] = c;
                    c3 = c2; c2 = c1; c1 = c;
                }
            }
        }
    }
    __syncthreads();

    // ---- evaluate: 256 threads x 8 points (2 float4 stores each) ----
    const int qd  = tid & 1;       // which 8-point half
    const int bcr = tid >> 1;      // bc row 0..127
    const int nb  = ns + (qd << 3);
    float Nv[8][4];
    int so[8];
#pragma unroll
    for (int j = 0; j < 8; ++j) {
        const int n = nb + j;
        const float xe = -1.0f + 2.0f * (float)n / 8191.0f;
        int off = (int)((xe + 1.0f) * 255.5f);
        off = off < 0 ? 0 : (off > NX - 2 ? NX - 2 : off);
        deboor3(xe, off + 3, Nv[j]);
        so[j] = off - i0;          // >= e_lo - i0 >= 0
    }
    const float* Cr = Bs + bcr * STRIDE + d;
    float4 r0, r1;
    r0.x = Nv[0][0] * Cr[so[0]] + Nv[0][1] * Cr[so[0] + 1] + Nv[0][2] * Cr[so[0] + 2] + Nv[0][3] * Cr[so[0] + 3];
    r0.y = Nv[1][0] * Cr[so[1]] + Nv[1][1] * Cr[so[1] + 1] + Nv[1][2] * Cr[so[1] + 2] + Nv[1][3] * Cr[so[1] + 3];
    r0.z = Nv[2][0] * Cr[so[2]] + Nv[2][1] * Cr[so[2] + 1] + Nv[2][2] * Cr[so[2] + 2] + Nv[2][3] * Cr[so[2] + 3];
    r0.w = Nv[3][0] * Cr[so[3]] + Nv[3][1] * Cr[so[3] + 1] + Nv[3][2] * Cr[so[3] + 2] + Nv[3][3] * Cr[so[3] + 3];
    r1.x = Nv[4][0] * Cr[so[4]] + Nv[4][1] * Cr[so[4] + 1] + Nv[4][2] * Cr[so[4] + 2] + Nv[4][3] * Cr[so[4] + 3];
    r1.y = Nv[5][0] * Cr[so[5]] + Nv[5][1] * Cr[so[5] + 1] + Nv[5][2] * Cr[so[5] + 2] + Nv[5][3] * Cr[so[5] + 3];
    r1.z = Nv[6][0] * Cr[so[6]] + Nv[6][1] * Cr[so[6] + 1] + Nv[6][2] * Cr[so[6] + 2] + Nv[6][3] * Cr[so[6] + 3];
    r1.w = Nv[7][0] * Cr[so[7]] + Nv[7][1] * Cr[so[7] + 1] + Nv[7][2] * Cr[so[7] + 2] + Nv[7][3] * Cr[so[7] + 3];
    float* op = out + (size_t)(bc0 + bcr) * NE + nb;
    *(float4*)op = r0;
    *(float4*)(op + 4) = r1;
}

}  // namespace

extern "C" void kernel_launch(void* const* d_in, const int* in_sizes, int n_in,
                              void* d_out, int out_size, void* d_ws, size_t ws_size,
                              hipStream_t stream) {
    const float* Z = (const float*)d_in[0];
    float* out = (float*)d_out;
    (void)d_ws; (void)ws_size;

    hipLaunchKernelGGL(spline_fused, dim3(NBLK), dim3(256), 0, stream, Z, out);
}

// Round 12
// 12.164 us; speedup vs baseline: 1.9417x; 1.9417x over previous
//
#include <hip/hip_runtime.h>
#include <math.h>

namespace {

constexpr int NX  = 512;    // data points
constexpr int M   = 514;    // basis functions
constexpr int NE  = 8192;   // eval points
constexpr int NBC = 256;    // batch*channels
constexpr int PPB = 16;     // eval points per block
constexpr int NBLK = NE / PPB;      // 512 blocks
constexpr int CHUNKS = 9;           // float4 chunks staged per bc row
constexpr int SLOTS  = CHUNKS * 4;  // 36 staged columns
constexpr int STRIDE = 37;          // odd -> conflict-free LDS rows
constexpr int TAPS = 27;            // H row support: j = i-13+t, t=0..26

// ---------------------------------------------------------------------------
// Compile-time H = (BtB + S I)^-1 Bt, truncated to 27 taps per row (decay
// ~0.268^d; truncation err ~4e-7). Edge rows via local solves (forward pass
// of e_i is exactly 0 below row i; backward warm-up 0.268^10); interior rows
// share one Toeplitz stencil.
// ---------------------------------------------------------------------------
constexpr double dknot(int j) {
    int c = j - 3;
    c = c < 0 ? 0 : (c > NX - 1 ? NX - 1 : c);
    return -1.0 + 2.0 * (double)c / 511.0;
}

constexpr double csqrt(double x) {
    double r = x > 1.0 ? x : 1.0;
    for (int k = 0; k < 50; ++k) r = 0.5 * (r + x / r);
    return r;
}

struct HTab { alignas(16) float h[M][28]; };   // [i][t], t=27 pad

constexpr HTab make_h() {
    HTab T{};
    // basis at data points (double de Boor)
    double bx[NX][4] = {};
    for (int n = 0; n < NX; ++n) {
        const int off = n < NX - 1 ? n : NX - 2;
        const double x = -1.0 + 2.0 * (double)n / 511.0;
        double N[4] = {1.0, 0.0, 0.0, 0.0};
        for (int dd = 1; dd <= 3; ++dd) {
            double saved = 0.0;
            for (int r = 0; r < dd; ++r) {
                const double tr = dknot(off + 3 + r + 1);
                const double tl = dknot(off + 3 + r + 1 - dd);
                const double temp = N[r] / (tr - tl);
                N[r] = saved + (tr - x) * temp;
                saved = (x - tl) * temp;
            }
            N[dd] = saved;
        }
        for (int r = 0; r < 4; ++r) bx[n][r] = N[r];
    }
    // banded BtB + S
    double A0[M] = {}, A1[M] = {}, A2[M] = {}, A3[M] = {};
    for (int i = 0; i < M; ++i) {
        double a0 = 1e-3, a1 = 0.0, a2 = 0.0, a3 = 0.0;
        const int nlo = i - 3 < 0 ? 0 : i - 3;
        const int nhi = i + 1 > NX - 1 ? NX - 1 : i + 1;
        for (int n = nlo; n <= nhi; ++n) {
            const int off = n < NX - 1 ? n : NX - 2;
            const int ri = i - off;
            if (ri < 0 || ri > 3) continue;
            const double bi = bx[n][ri];
            a0 += bi * bx[n][ri];
            if (ri >= 1) a1 += bi * bx[n][ri - 1];
            if (ri >= 2) a2 += bi * bx[n][ri - 2];
            if (ri >= 3) a3 += bi * bx[n][ri - 3];
        }
        A0[i] = a0; A1[i] = a1; A2[i] = a2; A3[i] = a3;
    }
    // banded Cholesky (ld = 1/diag), padded +3 with zeros
    double ld[M + 3] = {}, l1a[M + 3] = {}, l2a[M + 3] = {}, l3a[M + 3] = {};
    {
        double rd1 = 0.0, l1p = 0.0, l2p = 0.0, rd2 = 0.0, l1pp = 0.0, rd3 = 0.0;
        for (int i = 0; i < M; ++i) {
            const double l3 = A3[i] * rd3;
            const double l2 = (A2[i] - l3 * l1pp) * rd2;
            const double l1 = (A1[i] - l3 * l2p - l2 * l1p) * rd1;
            const double s  = A0[i] - l3 * l3 - l2 * l2 - l1 * l1;
            const double rd = 1.0 / csqrt(s);
            ld[i] = rd; l1a[i] = l1; l2a[i] = l2; l3a[i] = l3;
            rd3 = rd2; rd2 = rd1; rd1 = rd;
            l1pp = l1p; l1p = l1; l2p = l2;
        }
    }
    constexpr int ILO = 40, IHI = 473, IREF = 250;
    // per-row Green's column (local solve) + H assembly
    for (int i = 0; i < M; ++i) {
        const bool interior = (i >= ILO && i <= IHI);
        if (interior && i != IREF) continue;
        double y[44] = {};   // fwd solution, rows i-14+k; exactly 0 below i
        for (int k = 14; k < 44; ++k) {
            const int row = i - 14 + k;
            if (row >= M) break;
            const double b = (row == i) ? 1.0 : 0.0;
            const double ym1 = y[k - 1], ym2 = y[k - 2], ym3 = y[k - 3];
            y[k] = (b - l1a[row] * ym1 - l2a[row] * ym2 - l3a[row] * ym3) * ld[row];
        }
        double g[44] = {};   // G[i][i-14+k]
        for (int k = 43; k >= 0; --k) {
            const int row = i - 14 + k;
            if (row > M - 1) continue;
            if (row < 0) break;
            const double cp1 = k + 1 < 44 ? g[k + 1] : 0.0;
            const double cp2 = k + 2 < 44 ? g[k + 2] : 0.0;
            const double cp3 = k + 3 < 44 ? g[k + 3] : 0.0;
            g[k] = (y[k] - l1a[row + 1] * cp1 - l2a[row + 2] * cp2 - l3a[row + 3] * cp3) * ld[row];
        }
        for (int t = 0; t < TAPS; ++t) {
            const int j = i - 13 + t;
            double s = 0.0;
            if (j >= 0 && j <= NX - 1) {
                const int off = j < NX - 1 ? j : NX - 2;
                for (int r = 0; r < 4; ++r) {
                    const int idx = off + r;              // in [j, j+3]
                    const int k = idx - (i - 14);         // in [1, 30]
                    const double gv = (idx <= M - 1) ? g[k] : 0.0;
                    s += bx[j][r] * gv;
                }
            }
            T.h[i][t] = (float)s;
        }
        T.h[i][27] = 0.0f;
    }
    for (int i = ILO; i <= IHI; ++i) {
        if (i == IREF) continue;
        for (int t = 0; t < 28; ++t) T.h[i][t] = T.h[IREF][t];
    }
    return T;
}

__constant__ HTab HC = make_h();

// interval index of eval point n (single fp32 path everywhere)
__device__ __forceinline__ int offf(int n) {
    const float xe = -1.0f + 2.0f * (float)n / 8191.0f;
    int off = (int)((xe + 1.0f) * 255.5f);
    return off < 0 ? 0 : (off > NX - 2 ? NX - 2 : off);
}

__device__ __forceinline__ float knotf(int j) {
    int c = j - 3;
    c = c < 0 ? 0 : (c > NX - 1 ? NX - 1 : c);
    return -1.0f + 2.0f * (float)c / 511.0f;
}

__device__ __forceinline__ void deboor3(float x, int j, float N[4]) {
    N[0] = 1.0f; N[1] = 0.0f; N[2] = 0.0f; N[3] = 0.0f;
#pragma unroll
    for (int d = 1; d <= 3; ++d) {
        float saved = 0.0f;
#pragma unroll
        for (int r = 0; r < 3; ++r) {
            if (r < d) {
                const float tr = knotf(j + r + 1);
                const float tl = knotf(j + r + 1 - d);
                const float temp = N[r] / (tr - tl);
                N[r] = saved + (tr - x) * temp;
                saved = (x - tl) * temp;
            }
        }
        N[d] = saved;
    }
}

// ---------------------------------------------------------------------------
// Single fused kernel, chain-free. Block b: eval points [b*16, b*16+16) x all
// 256 bc. Stage Z window (9 float4/thread, R10 pattern) into LDS; 16 threads
// compute shared de Boor weights meanwhile; barrier; each thread (= one bc)
// reads its 31-col z row, forms 5 coef values as 27-tap dots with the
// __constant__ H stencil (wave-uniform rows -> scalar loads), evaluates its
// 16 points, writes 4 float4.
// ---------------------------------------------------------------------------
__global__ __launch_bounds__(256) void spline_fused(const float* __restrict__ Z,
                                                    float* __restrict__ out) {
    __shared__ float Bs[NBC * STRIDE + 8];
    __shared__ float NvS[PPB][8];     // Nv[4], so_rel
    const int tid = threadIdx.x;
    const int ns = blockIdx.x * PPB;

    // wave-uniform geometry
    const int e_lo = offf(ns);                 // first coef row needed
    const int n0 = e_lo - 13;                  // first needed Z column
    const int n0a = n0 & ~3;                   // aligned staging base
    const int d = n0 - n0a;                    // slot shift 0..3

    // ---- stage: 9 float4 loads/thread (8 coalesced chunks + remainder) ----
    {
        const int wid = tid >> 6, lane = tid & 63;
        const int rsub = lane >> 3;    // row within 8-row group
        const int ch = lane & 7;       // float4 chunk 0..7
        int cb = n0a + (ch << 2);
        cb = cb < 0 ? 0 : (cb > NX - 4 ? NX - 4 : cb);  // OOR slots have H=0
        int c8 = n0a + 32;
        c8 = c8 < 0 ? 0 : (c8 > NX - 4 ? NX - 4 : c8);

        float4 v[8], v8;
#pragma unroll
        for (int it = 0; it < 8; ++it) {
            const int row = (wid << 6) + (it << 3) + rsub;
            v[it] = *(const float4*)(Z + (size_t)row * NX + cb);
        }
        v8 = *(const float4*)(Z + (size_t)tid * NX + c8);

        // shared de Boor weights while loads are in flight
        if (tid < PPB) {
            const int n = ns + tid;
            const float xe = -1.0f + 2.0f * (float)n / 8191.0f;
            int off = (int)((xe + 1.0f) * 255.5f);
            off = off < 0 ? 0 : (off > NX - 2 ? NX - 2 : off);
            float N[4];
            deboor3(xe, off + 3, N);
            NvS[tid][0] = N[0]; NvS[tid][1] = N[1];
            NvS[tid][2] = N[2]; NvS[tid][3] = N[3];
            int sr = off - e_lo;
            sr = sr < 0 ? 0 : (sr > 1 ? 1 : sr);
            NvS[tid][4] = (float)sr;
        }

#pragma unroll
        for (int it = 0; it < 8; ++it) {
            const int row = (wid << 6) + (it << 3) + rsub;
            float* wp = Bs + row * STRIDE + (ch << 2);   // scalar writes, odd stride
            wp[0] = v[it].x; wp[1] = v[it].y; wp[2] = v[it].z; wp[3] = v[it].w;
        }
        {
            float* wp = Bs + tid * STRIDE + 32;
            wp[0] = v8.x; wp[1] = v8.y; wp[2] = v8.z; wp[3] = v8.w;
        }
    }
    __syncthreads();

    // ---- per-thread (= bc): z row -> 5 coef dots -> 16 eval points ----
    const float* Brow = Bs + tid * STRIDE + d;   // Brow[s] = Z col n0+s
    float z[31];
#pragma unroll
    for (int s = 0; s < 31; ++s) z[s] = Brow[s];

    float cf[5];
#pragma unroll
    for (int c = 0; c < 5; ++c) {
        int row = e_lo + c;
        row = row < M ? row : M - 1;             // clamped (unused when NC<5)
        const float* Hr = HC.h[row];             // wave-uniform -> scalar loads
        float acc = 0.0f;
#pragma unroll
        for (int t = 0; t < TAPS; ++t) acc += Hr[t] * z[c + t];
        cf[c] = acc;
    }

    float4 r[4];
#pragma unroll
    for (int p = 0; p < PPB; ++p) {
        const float w0 = NvS[p][0], w1 = NvS[p][1], w2 = NvS[p][2], w3 = NvS[p][3];
        const int sr = (int)NvS[p][4];           // wave-uniform branch
        float v;
        if (sr == 0) v = w0 * cf[0] + w1 * cf[1] + w2 * cf[2] + w3 * cf[3];
        else         v = w0 * cf[1] + w1 * cf[2] + w2 * cf[3] + w3 * cf[4];
        ((float*)&r[p >> 2])[p & 3] = v;
    }
    float* op = out + (size_t)tid * NE + ns;
    *(float4*)(op)      = r[0];
    *(float4*)(op + 4)  = r[1];
    *(float4*)(op + 8)  = r[2];
    *(float4*)(op + 12) = r[3];
}

}  // namespace

extern "C" void kernel_launch(void* const* d_in, const int* in_sizes, int n_in,
                              void* d_out, int out_size, void* d_ws, size_t ws_size,
                              hipStream_t stream) {
    const float* Z = (const float*)d_in[0];
    float* out = (float*)d_out;
    (void)d_ws; (void)ws_size;

    hipLaunchKernelGGL(spline_fused, dim3(NBLK), dim3(256), 0, stream, Z, out);
}